// Round 1
// baseline (68.362 us; speedup 1.0000x reference)
//
#include <hip/hip_runtime.h>
#include <hip/hip_bf16.h>

#define B_ROWS 8192
#define E_DIM  1024
#define MARGIN 0.2f

typedef __bf16 bf16x8 __attribute__((ext_vector_type(8)));
typedef float  f32x4  __attribute__((ext_vector_type(4)));

__device__ __forceinline__ void gload_lds16(const void* g, void* l) {
    __builtin_amdgcn_global_load_lds(
        (__attribute__((address_space(1))) void*)(g),
        (__attribute__((address_space(3))) void*)(l),
        16, 0, 0);
}

// c = 0.4*m + 0.6*tr_m, fp32 -> bf16, 8 elems/thread
__global__ void prep_c(const float* __restrict__ m, const float* __restrict__ trm,
                       __bf16* __restrict__ c) {
    size_t i = ((size_t)blockIdx.x * blockDim.x + threadIdx.x) * 8;
    float4 m0 = *(const float4*)(m + i);
    float4 m1 = *(const float4*)(m + i + 4);
    float4 t0 = *(const float4*)(trm + i);
    float4 t1 = *(const float4*)(trm + i + 4);
    bf16x8 v;
    v[0] = (__bf16)(0.4f*m0.x + 0.6f*t0.x);
    v[1] = (__bf16)(0.4f*m0.y + 0.6f*t0.y);
    v[2] = (__bf16)(0.4f*m0.z + 0.6f*t0.z);
    v[3] = (__bf16)(0.4f*m0.w + 0.6f*t0.w);
    v[4] = (__bf16)(0.4f*m1.x + 0.6f*t1.x);
    v[5] = (__bf16)(0.4f*m1.y + 0.6f*t1.y);
    v[6] = (__bf16)(0.4f*m1.z + 0.6f*t1.z);
    v[7] = (__bf16)(0.4f*m1.w + 0.6f*t1.w);
    *(bf16x8*)(c + i) = v;
}

// Wt[n][e] = (bf16) W[e][n]  -- makes GEMM B-operand contiguous along K(=e)
__global__ void transpose_w(const float* __restrict__ W, __bf16* __restrict__ Wt) {
    __shared__ __bf16 tile[32][33];
    int tx = threadIdx.x, ty = threadIdx.y;
    int bx = blockIdx.x * 32;   // n base
    int by = blockIdx.y * 32;   // e base
    tile[ty][tx] = (__bf16)W[(size_t)(by + ty) * E_DIM + bx + tx];
    __syncthreads();
    Wt[(size_t)(bx + ty) * E_DIM + by + tx] = tile[tx][ty];
}

// u = c @ W  (via Wt, B^T layout), fused rowwise dot with (A_is - A_em),
// atomicAdd partial row sums into delta[B_ROWS].
// 128x128 tile, BK=32, 4 waves (2x2 of 64x64), mfma_f32_16x16x32_bf16.
__global__ __launch_bounds__(256)
void gemm_dot(const __bf16* __restrict__ Cm, const __bf16* __restrict__ Wt,
              const float* __restrict__ Ais, const float* __restrict__ Aem,
              float* __restrict__ delta) {
    __shared__ __bf16 As[128 * 32];  // [row][k] linear, 8 KiB
    __shared__ __bf16 Bs[128 * 32];  // [col][k] linear, 8 KiB

    const int tid  = threadIdx.x;
    const int lane = tid & 63;
    const int wave = tid >> 6;
    const int brow = (blockIdx.x >> 3) * 128;
    const int bcol = (blockIdx.x & 7) * 128;

    const int wr = wave >> 1, wc = wave & 1;
    const int lr = lane & 15;
    const int lk = (lane >> 4) * 8;

    f32x4 acc[4][4] = {};

    for (int k0 = 0; k0 < E_DIM; k0 += 32) {
#pragma unroll
        for (int i = 0; i < 2; ++i) {
            int o   = i * 4096 + wave * 1024 + lane * 16; // byte offset in tile
            int row = o >> 6;                             // 64 B per 32-bf16 row
            int kb  = o & 63;
            const char* gA = (const char*)Cm + ((size_t)(brow + row) * E_DIM + k0) * 2 + kb;
            const char* gB = (const char*)Wt + ((size_t)(bcol + row) * E_DIM + k0) * 2 + kb;
            gload_lds16(gA, (char*)As + i * 4096 + wave * 1024);
            gload_lds16(gB, (char*)Bs + i * 4096 + wave * 1024);
        }
        __syncthreads();   // compiler drains vmcnt before barrier

        bf16x8 a[4], b[4];
#pragma unroll
        for (int mi = 0; mi < 4; ++mi)
            a[mi] = *(const bf16x8*)(As + (wr * 64 + mi * 16 + lr) * 32 + lk);
#pragma unroll
        for (int ni = 0; ni < 4; ++ni)
            b[ni] = *(const bf16x8*)(Bs + (wc * 64 + ni * 16 + lr) * 32 + lk);

#pragma unroll
        for (int mi = 0; mi < 4; ++mi)
#pragma unroll
            for (int ni = 0; ni < 4; ++ni)
                acc[mi][ni] = __builtin_amdgcn_mfma_f32_16x16x32_bf16(
                    a[mi], b[ni], acc[mi][ni], 0, 0, 0);
        __syncthreads();
    }

    // Epilogue: delta[r] += sum_c u[r][c] * (Ais - Aem)[r][c] over this block's cols.
    // C/D layout (16x16x32): col = lane&15, row = (lane>>4)*4 + reg.
    const int colbase = bcol + wc * 64 + lr;
    const int rowbase = brow + wr * 64 + (lane >> 4) * 4;
#pragma unroll
    for (int mi = 0; mi < 4; ++mi) {
#pragma unroll
        for (int j = 0; j < 4; ++j) {
            int r = rowbase + mi * 16 + j;
            float v = 0.f;
#pragma unroll
            for (int ni = 0; ni < 4; ++ni) {
                size_t idx = (size_t)r * E_DIM + colbase + ni * 16;
                v += acc[mi][ni][j] * (Ais[idx] - Aem[idx]);
            }
            // reduce across the 16 lanes of this col-group (xor bits 0..3)
            v += __shfl_xor(v, 1);
            v += __shfl_xor(v, 2);
            v += __shfl_xor(v, 4);
            v += __shfl_xor(v, 8);
            if (lr == 0) atomicAdd(&delta[r], v);
        }
    }
}

__global__ void hinge_sum(const float* __restrict__ delta, float* __restrict__ out) {
    float s = 0.f;
    for (int i = threadIdx.x; i < B_ROWS; i += 256)
        s += fmaxf(MARGIN + delta[i], 0.f);
#pragma unroll
    for (int off = 32; off > 0; off >>= 1) s += __shfl_down(s, off);
    __shared__ float wsum[4];
    int lane = threadIdx.x & 63, w = threadIdx.x >> 6;
    if (lane == 0) wsum[w] = s;
    __syncthreads();
    if (threadIdx.x == 0) out[0] = wsum[0] + wsum[1] + wsum[2] + wsum[3];
}

extern "C" void kernel_launch(void* const* d_in, const int* in_sizes, int n_in,
                              void* d_out, int out_size, void* d_ws, size_t ws_size,
                              hipStream_t stream) {
    const float* A_is = (const float*)d_in[0];
    const float* A_em = (const float*)d_in[1];
    const float* m    = (const float*)d_in[2];
    const float* tr_m = (const float*)d_in[3];
    const float* W    = (const float*)d_in[4];
    // d_in[5] = b : bias cancels in diag_is - diag_em, unused.
    float* out = (float*)d_out;

    char* ws = (char*)d_ws;
    __bf16* c     = (__bf16*)ws;                                  // 16 MiB
    __bf16* wt    = (__bf16*)(ws + (size_t)16 * 1024 * 1024);     //  2 MiB
    float*  delta = (float*) (ws + (size_t)18 * 1024 * 1024);     // 32 KiB

    hipMemsetAsync(delta, 0, B_ROWS * sizeof(float), stream);
    prep_c<<<4096, 256, 0, stream>>>(m, tr_m, c);
    transpose_w<<<dim3(32, 32), dim3(32, 32), 0, stream>>>(W, wt);
    gemm_dot<<<512, 256, 0, stream>>>(c, wt, A_is, A_em, delta);
    hinge_sum<<<1, 256, 0, stream>>>(delta, out);
}